// Round 1
// baseline (666.354 us; speedup 1.0000x reference)
//
#include <hip/hip_runtime.h>
#include <hip/hip_bf16.h>

#define B_SIZE 4096
#define D_SIZE 256
#define N_SIZE 8192
#define TEMP_INV 10.0f

typedef __attribute__((ext_vector_type(8))) short short8;
typedef __attribute__((ext_vector_type(4))) float floatx4;

// ws layout (bytes):
//      0 : int   cnt[128]        (512 B)   -- label histogram
//    512 : float S[2*8192]       (65536)   -- per-row exp-sum, per teacher
//  66048 : float A[2*8192]       (65536)   -- per-row masked sim-sum
// 131584 : bf16  featS [4096*256] (2 MB)
// 2228736: bf16  featT0[4096*256] (2 MB)
// 4325888: bf16  featT1[4096*256] (2 MB)
// total: 6423040 bytes

__global__ void hist_kernel(const int* __restrict__ labels, int* __restrict__ cnt) {
    __shared__ int h[128];
    int tid = threadIdx.x;
    if (tid < 128) h[tid] = 0;
    __syncthreads();
    for (int i = tid; i < B_SIZE; i += 256) atomicAdd(&h[labels[i] & 127], 1);
    __syncthreads();
    if (tid < 128) cnt[tid] = h[tid];
}

__global__ void norm_kernel(const float* __restrict__ src, __hip_bfloat16* __restrict__ dst) {
    int row = blockIdx.x;
    int tid = threadIdx.x;
    float x = src[row * D_SIZE + tid];
    float ss = x * x;
#pragma unroll
    for (int off = 32; off > 0; off >>= 1) ss += __shfl_xor(ss, off);
    __shared__ float wsum[4];
    int wave = tid >> 6, lane = tid & 63;
    if (lane == 0) wsum[wave] = ss;
    __syncthreads();
    float tot = wsum[0] + wsum[1] + wsum[2] + wsum[3];
    float n = sqrtf(tot);
    float inv = 1.0f / fmaxf(n, 1e-12f);
    dst[row * D_SIZE + tid] = __float2bfloat16(x * inv);
}

// sim row-stat kernel: grid (128 row-blocks, 2 teachers, 2 column halves), 256 thr.
// Each wave owns 16 rows; A fragments (full K=256) stay in registers; loop over
// 16-wide column tiles, 8 MFMAs per tile, fused masked-softmax-stat epilogue.
__global__ __launch_bounds__(256)
void sim_kernel(const __hip_bfloat16* __restrict__ featS,
                const __hip_bfloat16* __restrict__ featT0,
                const __hip_bfloat16* __restrict__ featT1,
                const int* __restrict__ labels,
                float* __restrict__ Sarr,
                float* __restrict__ Aarr) {
    const int rb   = blockIdx.x;   // row block of 64
    const int t    = blockIdx.y;   // teacher index
    const int half = blockIdx.z;   // column half
    const __hip_bfloat16* featT = t ? featT1 : featT0;

    const int tid  = threadIdx.x;
    const int wave = tid >> 6;
    const int lane = tid & 63;
    const int quad = lane >> 4;
    const int lcol = lane & 15;

    const int row_base = rb * 64 + wave * 16;

    // A-operand: lane holds A[m=lane&15][k=quad*8+j] for each 32-wide k-step
    const int arow = row_base + lcol;
    const __hip_bfloat16* aptr = (arow < B_SIZE) ? (featS + arow * D_SIZE)
                                                 : (featT + (arow - B_SIZE) * D_SIZE);
    short8 afrag[8];
#pragma unroll
    for (int ks = 0; ks < 8; ++ks)
        afrag[ks] = *reinterpret_cast<const short8*>(aptr + ks * 32 + quad * 8);

    // labels of the 4 rows this lane accumulates (C/D layout: row=quad*4+r)
    int labr[4];
#pragma unroll
    for (int r = 0; r < 4; ++r)
        labr[r] = labels[(row_base + quad * 4 + r) & (B_SIZE - 1)];

    float Sp[4] = {0.f, 0.f, 0.f, 0.f};
    float Ap[4] = {0.f, 0.f, 0.f, 0.f};

    const int col_start = half * (N_SIZE / 2);
    const int col_end   = col_start + (N_SIZE / 2);

    for (int cb = col_start; cb < col_end; cb += 16) {
        const int bcol = cb + lcol;  // B-frag row == epilogue column (same lane&15)
        const __hip_bfloat16* bptr = (bcol < B_SIZE) ? (featS + bcol * D_SIZE)
                                                     : (featT + (bcol - B_SIZE) * D_SIZE);
        floatx4 acc = {0.f, 0.f, 0.f, 0.f};
#pragma unroll
        for (int ks = 0; ks < 8; ++ks) {
            short8 bfrag = *reinterpret_cast<const short8*>(bptr + ks * 32 + quad * 8);
            acc = __builtin_amdgcn_mfma_f32_16x16x32_bf16(afrag[ks], bfrag, acc, 0, 0, 0);
        }
        const int labj = labels[bcol & (B_SIZE - 1)];
#pragma unroll
        for (int r = 0; r < 4; ++r) {
            const int row = row_base + quad * 4 + r;
            const float sim = acc[r] * TEMP_INV;
            const float e = __expf(sim);
            const bool diag = (row == bcol);
            Sp[r] += diag ? 0.f : e;
            Ap[r] += (!diag && (labj == labr[r])) ? sim : 0.f;
        }
    }

    // reduce across the 16 lanes holding different columns of each row
#pragma unroll
    for (int r = 0; r < 4; ++r) {
#pragma unroll
        for (int m = 1; m < 16; m <<= 1) {
            Sp[r] += __shfl_xor(Sp[r], m);
            Ap[r] += __shfl_xor(Ap[r], m);
        }
    }
    if (lcol == 0) {
#pragma unroll
        for (int r = 0; r < 4; ++r) {
            const int row = row_base + quad * 4 + r;
            atomicAdd(&Sarr[t * N_SIZE + row], Sp[r]);
            atomicAdd(&Aarr[t * N_SIZE + row], Ap[r]);
        }
    }
}

__global__ void final_kernel(const float* __restrict__ Sarr,
                             const float* __restrict__ Aarr,
                             const int* __restrict__ cnt,
                             const int* __restrict__ labels,
                             float* __restrict__ out) {
    int tid = threadIdx.x;
    float acc = 0.f;
    for (int idx = tid; idx < 2 * N_SIZE; idx += 256) {
        int i = idx & (N_SIZE - 1);
        float M = 2.0f * (float)cnt[labels[i & (B_SIZE - 1)] & 127] - 1.0f;
        acc += logf(Sarr[idx]) - Aarr[idx] / M;
    }
#pragma unroll
    for (int off = 32; off > 0; off >>= 1) acc += __shfl_xor(acc, off);
    __shared__ float wsum[4];
    int wave = tid >> 6, lane = tid & 63;
    if (lane == 0) wsum[wave] = acc;
    __syncthreads();
    if (tid == 0) out[0] = (wsum[0] + wsum[1] + wsum[2] + wsum[3]) / 16384.0f;
}

extern "C" void kernel_launch(void* const* d_in, const int* in_sizes, int n_in,
                              void* d_out, int out_size, void* d_ws, size_t ws_size,
                              hipStream_t stream) {
    const float* hs    = (const float*)d_in[0];
    const float* ht0   = (const float*)d_in[1];
    const float* ht1   = (const float*)d_in[2];
    const int*   labels = (const int*)d_in[3];

    char* ws = (char*)d_ws;
    int*   cnt  = (int*)ws;
    float* Sarr = (float*)(ws + 512);
    float* Aarr = (float*)(ws + 66048);
    __hip_bfloat16* featS  = (__hip_bfloat16*)(ws + 131584);
    __hip_bfloat16* featT0 = (__hip_bfloat16*)(ws + 131584 + 2097152);
    __hip_bfloat16* featT1 = (__hip_bfloat16*)(ws + 131584 + 2 * 2097152);

    // zero cnt + S + A (ws is poisoned 0xAA before every timed launch)
    hipMemsetAsync(d_ws, 0, 131584, stream);

    hist_kernel<<<1, 256, 0, stream>>>(labels, cnt);
    norm_kernel<<<4096, 256, 0, stream>>>(hs, featS);
    norm_kernel<<<4096, 256, 0, stream>>>(ht0, featT0);
    norm_kernel<<<4096, 256, 0, stream>>>(ht1, featT1);
    sim_kernel<<<dim3(128, 2, 2), 256, 0, stream>>>(featS, featT0, featT1, labels, Sarr, Aarr);
    final_kernel<<<1, 256, 0, stream>>>(Sarr, Aarr, cnt, labels, (float*)d_out);
}

// Round 2
// 575.250 us; speedup vs baseline: 1.1584x; 1.1584x over previous
//
#include <hip/hip_runtime.h>
#include <hip/hip_bf16.h>

#define B_SIZE 4096
#define D_SIZE 256
#define N_SIZE 8192
#define TEMP_INV 10.0f
#define NCHUNK 8                       // column chunks (grid.z)
#define CHUNK (N_SIZE / NCHUNK)        // 1024 columns per block

typedef __attribute__((ext_vector_type(8))) short short8;
typedef __attribute__((ext_vector_type(4))) float floatx4;

// ws layout (bytes):
//      0 : int   cnt[128]        (512 B)   -- label histogram
//    512 : float S[2*8192]       (65536)   -- per-row exp-sum, per teacher
//  66048 : float A[2*8192]       (65536)   -- per-row masked sim-sum
// 131584 : bf16  featS [4096*256] (2 MB)   -- contiguous: featS|featT0|featT1
// 2228736: bf16  featT0[4096*256] (2 MB)
// 4325888: bf16  featT1[4096*256] (2 MB)

__global__ void hist_kernel(const int* __restrict__ labels, int* __restrict__ cnt) {
    __shared__ int h[128];
    int tid = threadIdx.x;
    if (tid < 128) h[tid] = 0;
    __syncthreads();
    for (int i = tid; i < B_SIZE; i += 256) atomicAdd(&h[labels[i] & 127], 1);
    __syncthreads();
    if (tid < 128) cnt[tid] = h[tid];
}

// One launch normalizes all 3 feature sets (12288 rows); dst buffers are contiguous.
__global__ void norm_kernel(const float* __restrict__ hs,
                            const float* __restrict__ ht0,
                            const float* __restrict__ ht1,
                            __hip_bfloat16* __restrict__ dst) {
    int id  = blockIdx.x;
    int tid = threadIdx.x;
    const float* src = (id < 4096) ? (hs + id * D_SIZE)
                     : (id < 8192) ? (ht0 + (id - 4096) * D_SIZE)
                                   : (ht1 + (id - 8192) * D_SIZE);
    float x = src[tid];
    float ss = x * x;
#pragma unroll
    for (int off = 32; off > 0; off >>= 1) ss += __shfl_xor(ss, off);
    __shared__ float wsum[4];
    int wave = tid >> 6, lane = tid & 63;
    if (lane == 0) wsum[wave] = ss;
    __syncthreads();
    float tot = wsum[0] + wsum[1] + wsum[2] + wsum[3];
    float inv = 1.0f / fmaxf(sqrtf(tot), 1e-12f);
    dst[id * D_SIZE + tid] = __float2bfloat16(x * inv);
}

// sim row-stat kernel: grid (128 row-blocks, 2 teachers, 8 column chunks), 256 thr.
// Each wave owns 16 rows (A-fragments register-resident, full K=256); iterates
// 64-column groups = 4 independent 16-col MFMA chains (ILP=4); fused epilogue
// accumulates per-row exp-sum and masked sim-sum in registers.
__global__ __launch_bounds__(256)
void sim_kernel(const __hip_bfloat16* __restrict__ featS,
                const __hip_bfloat16* __restrict__ featT0,
                const __hip_bfloat16* __restrict__ featT1,
                const int* __restrict__ labels,
                float* __restrict__ Sarr,
                float* __restrict__ Aarr) {
    const int rb    = blockIdx.x;
    const int t     = blockIdx.y;
    const int chunk = blockIdx.z;
    const __hip_bfloat16* featT = t ? featT1 : featT0;

    const int tid  = threadIdx.x;
    const int wave = tid >> 6;
    const int lane = tid & 63;
    const int quad = lane >> 4;
    const int lcol = lane & 15;

    const int row_base = rb * 64 + wave * 16;

    // A-operand: lane holds A[m=lane&15][k=quad*8+j] for each 32-wide k-step
    const int arow = row_base + lcol;
    const __hip_bfloat16* aptr = (arow < B_SIZE) ? (featS + arow * D_SIZE)
                                                 : (featT + (arow - B_SIZE) * D_SIZE);
    short8 afrag[8];
#pragma unroll
    for (int ks = 0; ks < 8; ++ks)
        afrag[ks] = *reinterpret_cast<const short8*>(aptr + ks * 32 + quad * 8);

    // labels of the 4 rows this lane accumulates (C/D layout: row=quad*4+r)
    int labr[4];
#pragma unroll
    for (int r = 0; r < 4; ++r)
        labr[r] = labels[(row_base + quad * 4 + r) & (B_SIZE - 1)];

    float Sp[4] = {0.f, 0.f, 0.f, 0.f};
    float Ap[4] = {0.f, 0.f, 0.f, 0.f};

    const int col_start = chunk * CHUNK;

    for (int cb = col_start; cb < col_start + CHUNK; cb += 64) {
        int bcol[4];
        const __hip_bfloat16* bptr[4];
#pragma unroll
        for (int u = 0; u < 4; ++u) {
            bcol[u] = cb + u * 16 + lcol;
            bptr[u] = (bcol[u] < B_SIZE) ? (featS + bcol[u] * D_SIZE)
                                         : (featT + (bcol[u] - B_SIZE) * D_SIZE);
        }
        floatx4 acc[4];
#pragma unroll
        for (int u = 0; u < 4; ++u) acc[u] = floatx4{0.f, 0.f, 0.f, 0.f};

#pragma unroll
        for (int ks = 0; ks < 8; ++ks) {
            short8 bf[4];
#pragma unroll
            for (int u = 0; u < 4; ++u)
                bf[u] = *reinterpret_cast<const short8*>(bptr[u] + ks * 32 + quad * 8);
#pragma unroll
            for (int u = 0; u < 4; ++u)
                acc[u] = __builtin_amdgcn_mfma_f32_16x16x32_bf16(afrag[ks], bf[u], acc[u], 0, 0, 0);
        }

#pragma unroll
        for (int u = 0; u < 4; ++u) {
            const int labj = labels[bcol[u] & (B_SIZE - 1)];
#pragma unroll
            for (int r = 0; r < 4; ++r) {
                const int row = row_base + quad * 4 + r;
                const float sim = acc[u][r] * TEMP_INV;
                const float e = __expf(sim);
                const bool diag = (row == bcol[u]);
                Sp[r] += diag ? 0.f : e;
                Ap[r] += (!diag && (labj == labr[r])) ? sim : 0.f;
            }
        }
    }

    // reduce across the 16 lanes holding different columns of each row
#pragma unroll
    for (int r = 0; r < 4; ++r) {
#pragma unroll
        for (int m = 1; m < 16; m <<= 1) {
            Sp[r] += __shfl_xor(Sp[r], m);
            Ap[r] += __shfl_xor(Ap[r], m);
        }
    }
    if (lcol == 0) {
#pragma unroll
        for (int r = 0; r < 4; ++r) {
            const int row = row_base + quad * 4 + r;
            atomicAdd(&Sarr[t * N_SIZE + row], Sp[r]);
            atomicAdd(&Aarr[t * N_SIZE + row], Ap[r]);
        }
    }
}

__global__ void final_kernel(const float* __restrict__ Sarr,
                             const float* __restrict__ Aarr,
                             const int* __restrict__ cnt,
                             const int* __restrict__ labels,
                             float* __restrict__ out) {
    int tid = threadIdx.x;
    float acc = 0.f;
    for (int idx = tid; idx < 2 * N_SIZE; idx += 256) {
        int i = idx & (N_SIZE - 1);
        float M = 2.0f * (float)cnt[labels[i & (B_SIZE - 1)] & 127] - 1.0f;
        acc += logf(Sarr[idx]) - Aarr[idx] / M;
    }
#pragma unroll
    for (int off = 32; off > 0; off >>= 1) acc += __shfl_xor(acc, off);
    __shared__ float wsum[4];
    int wave = tid >> 6, lane = tid & 63;
    if (lane == 0) wsum[wave] = acc;
    __syncthreads();
    if (tid == 0) out[0] = (wsum[0] + wsum[1] + wsum[2] + wsum[3]) / 16384.0f;
}

extern "C" void kernel_launch(void* const* d_in, const int* in_sizes, int n_in,
                              void* d_out, int out_size, void* d_ws, size_t ws_size,
                              hipStream_t stream) {
    const float* hs     = (const float*)d_in[0];
    const float* ht0    = (const float*)d_in[1];
    const float* ht1    = (const float*)d_in[2];
    const int*   labels = (const int*)d_in[3];

    char* ws = (char*)d_ws;
    int*   cnt  = (int*)ws;
    float* Sarr = (float*)(ws + 512);
    float* Aarr = (float*)(ws + 66048);
    __hip_bfloat16* featS  = (__hip_bfloat16*)(ws + 131584);
    __hip_bfloat16* featT0 = (__hip_bfloat16*)(ws + 131584 + 2097152);
    __hip_bfloat16* featT1 = (__hip_bfloat16*)(ws + 131584 + 2 * 2097152);

    // zero cnt + S + A (ws is poisoned 0xAA before every timed launch)
    hipMemsetAsync(d_ws, 0, 131584, stream);

    hist_kernel<<<1, 256, 0, stream>>>(labels, cnt);
    norm_kernel<<<3 * 4096, 256, 0, stream>>>(hs, ht0, ht1, featS);
    sim_kernel<<<dim3(128, 2, NCHUNK), 256, 0, stream>>>(featS, featT0, featT1, labels, Sarr, Aarr);
    final_kernel<<<1, 256, 0, stream>>>(Sarr, Aarr, cnt, labels, (float*)d_out);
}

// Round 3
// 170.221 us; speedup vs baseline: 3.9146x; 3.3794x over previous
//
#include <hip/hip_runtime.h>
#include <hip/hip_bf16.h>

#define B_SIZE 4096
#define D_SIZE 256
#define N_SIZE 8192
#define NCHUNK 8
#define CHUNK (N_SIZE / NCHUNK)   // 1024 cols per block
#define GROUP 64                  // cols per staged LDS group
#define NGROUPS (CHUNK / GROUP)   // 16

typedef __attribute__((ext_vector_type(8))) short short8;
typedef __attribute__((ext_vector_type(4))) float floatx4;

// ws layout (bytes):
//       0 : float S[2*8192]   (65536)  -- per-row exp-sum (atomic accum, zeroed by norm)
//   65536 : float A[2*8192]   (65536)  -- per-row masked raw-sim sum
//  131072 : bf16 featS [4096*256] (2MB)
// 2228224 : bf16 featT0[4096*256] (2MB)
// 4325376 : bf16 featT1[4096*256] (2MB)

__device__ __forceinline__ void async16(void* lds, const void* g) {
    __builtin_amdgcn_global_load_lds(
        (const __attribute__((address_space(1))) unsigned int*)g,
        (__attribute__((address_space(3))) unsigned int*)lds, 16, 0, 0);
}
__device__ __forceinline__ void async4(void* lds, const void* g) {
    __builtin_amdgcn_global_load_lds(
        (const __attribute__((address_space(1))) unsigned int*)g,
        (__attribute__((address_space(3))) unsigned int*)lds, 4, 0, 0);
}

// Normalize all 3 feature sets; blocks 0..127 also zero the S/A accumulators.
__global__ void norm_kernel(const float* __restrict__ hs,
                            const float* __restrict__ ht0,
                            const float* __restrict__ ht1,
                            __hip_bfloat16* __restrict__ dst,
                            float* __restrict__ zero_region) {
    int id  = blockIdx.x;
    int tid = threadIdx.x;
    int gid = id * 256 + tid;
    if (gid < 2 * 2 * N_SIZE) zero_region[gid] = 0.0f;  // 32768 floats = S+A

    const float* src = (id < 4096) ? (hs + id * D_SIZE)
                     : (id < 8192) ? (ht0 + (id - 4096) * D_SIZE)
                                   : (ht1 + (id - 8192) * D_SIZE);
    float x = src[tid];
    float ss = x * x;
#pragma unroll
    for (int off = 32; off > 0; off >>= 1) ss += __shfl_xor(ss, off);
    __shared__ float wsum[4];
    int wave = tid >> 6, lane = tid & 63;
    if (lane == 0) wsum[wave] = ss;
    __syncthreads();
    float tot = wsum[0] + wsum[1] + wsum[2] + wsum[3];
    float inv = 1.0f / fmaxf(sqrtf(tot), 1e-12f);
    dst[id * D_SIZE + tid] = __float2bfloat16(x * inv);
}

// grid (64 row-blocks of 128, 2 teachers, NCHUNK col chunks), 256 threads.
// Wave owns 32 rows (2 row-tiles, A register-resident full-K). 64-col groups
// staged into LDS (dbuf) via global_load_lds with XOR-swizzled 16B chunks
// (key = col&7) so ds_read_b128 fragment reads are bank-conflict-free.
// Staging for group g+1 is issued BEFORE compute of group g.
__global__ __launch_bounds__(256)
void sim_kernel(const __hip_bfloat16* __restrict__ featS,
                const __hip_bfloat16* __restrict__ featT0,
                const __hip_bfloat16* __restrict__ featT1,
                const int* __restrict__ labels,
                float* __restrict__ Sarr,
                float* __restrict__ Aarr) {
    __shared__ __align__(16) unsigned char sB[2][32768];  // 64 cols x 512 B
    __shared__ int sLab[2][GROUP];

    const int rb    = blockIdx.x;
    const int t     = blockIdx.y;
    const int chunk = blockIdx.z;
    const __hip_bfloat16* featT = t ? featT1 : featT0;

    const int tid  = threadIdx.x;
    const int w    = tid >> 6;
    const int l    = tid & 63;
    const int quad = l >> 4;
    const int lcol = l & 15;
    const int row_base = rb * 128 + w * 32;

    // A fragments: 2 row-tiles x 8 k-steps, register resident (one-time global load)
    short8 af[2][8];
#pragma unroll
    for (int rt = 0; rt < 2; ++rt) {
        int arow = row_base + rt * 16 + lcol;
        const __hip_bfloat16* ap = (arow < B_SIZE) ? featS + arow * D_SIZE
                                                   : featT + (arow - B_SIZE) * D_SIZE;
#pragma unroll
        for (int ks = 0; ks < 8; ++ks)
            af[rt][ks] = *reinterpret_cast<const short8*>(ap + ks * 32 + quad * 8);
    }

    int labr[2][4];
#pragma unroll
    for (int rt = 0; rt < 2; ++rt)
#pragma unroll
        for (int r = 0; r < 4; ++r)
            labr[rt][r] = labels[(row_base + rt * 16 + quad * 4 + r) & (B_SIZE - 1)];

    float Sp[2][4] = {{0.f,0.f,0.f,0.f},{0.f,0.f,0.f,0.f}};
    float Ap[2][4] = {{0.f,0.f,0.f,0.f},{0.f,0.f,0.f,0.f}};

    const int col0 = chunk * CHUNK;

    // stage a 64-col group into buffer b: wave w stages cols [w*16, w*16+16).
    // LDS byte (region w) = i*1024 + lane*16 -> col cl = i*2+(lane>>5), swizzled
    // chunk c' = lane&31 holding global chunk c = c' ^ (cl&7).
    auto stage = [&](int b, int cb) {
#pragma unroll
        for (int i = 0; i < 8; ++i) {
            int cl  = i * 2 + (l >> 5);
            int c   = (l & 31) ^ (cl & 7);
            int col = cb + w * 16 + cl;
            const __hip_bfloat16* cp = (col < B_SIZE) ? featS + col * D_SIZE
                                                      : featT + (col - B_SIZE) * D_SIZE;
            async16(&sB[b][w * 8192 + i * 1024], (const char*)cp + c * 16);
        }
        if (w == 0) async4(&sLab[b][0], &labels[(cb + l) & (B_SIZE - 1)]);
    };

    stage(0, col0);

    for (int g = 0; g < NGROUPS; ++g) {
        const int buf = g & 1;
        const int cb  = col0 + g * GROUP;
        __syncthreads();                       // drains vmcnt -> buf staged; protects buf^1 reuse
        if (g + 1 < NGROUPS) stage(buf ^ 1, cb + GROUP);  // async, flies during compute

        floatx4 acc[4][2];
#pragma unroll
        for (int u = 0; u < 4; ++u)
#pragma unroll
            for (int rt = 0; rt < 2; ++rt)
                acc[u][rt] = floatx4{0.f, 0.f, 0.f, 0.f};

#pragma unroll
        for (int ks = 0; ks < 8; ++ks) {
            short8 bf[4];
#pragma unroll
            for (int u = 0; u < 4; ++u)
                bf[u] = *reinterpret_cast<const short8*>(
                    &sB[buf][u * 8192 + lcol * 512 + ((ks * 4 + quad) ^ (lcol & 7)) * 16]);
#pragma unroll
            for (int u = 0; u < 4; ++u)
#pragma unroll
                for (int rt = 0; rt < 2; ++rt)
                    acc[u][rt] = __builtin_amdgcn_mfma_f32_16x16x32_bf16(
                        af[rt][ks], bf[u], acc[u][rt], 0, 0, 0);
        }

        // fused epilogue: per-row exp-sum and masked raw-sim sum (x10 deferred)
#pragma unroll
        for (int u = 0; u < 4; ++u) {
            const int bcol = cb + u * 16 + lcol;
            const int labj = sLab[buf][u * 16 + lcol];
#pragma unroll
            for (int rt = 0; rt < 2; ++rt)
#pragma unroll
                for (int r = 0; r < 4; ++r) {
                    const int row = row_base + rt * 16 + quad * 4 + r;
                    const float a = acc[u][rt][r];
                    const float e = __expf(a * 10.0f);
                    const bool diag = (row == bcol);
                    Sp[rt][r] += diag ? 0.f : e;
                    Ap[rt][r] += (!diag && labj == labr[rt][r]) ? a : 0.f;
                }
        }
    }

    // reduce across the 16 lanes (same quad) holding different columns
#pragma unroll
    for (int rt = 0; rt < 2; ++rt)
#pragma unroll
        for (int r = 0; r < 4; ++r) {
#pragma unroll
            for (int m = 1; m < 16; m <<= 1) {
                Sp[rt][r] += __shfl_xor(Sp[rt][r], m);
                Ap[rt][r] += __shfl_xor(Ap[rt][r], m);
            }
        }
    if (lcol == 0) {
#pragma unroll
        for (int rt = 0; rt < 2; ++rt)
#pragma unroll
            for (int r = 0; r < 4; ++r) {
                const int row = row_base + rt * 16 + quad * 4 + r;
                atomicAdd(&Sarr[t * N_SIZE + row], Sp[rt][r]);
                atomicAdd(&Aarr[t * N_SIZE + row], Ap[rt][r]);
            }
    }
}

// 1 block, 1024 threads: label histogram in LDS, then final loss reduction.
__global__ void final_kernel(const float* __restrict__ Sarr,
                             const float* __restrict__ Aarr,
                             const int* __restrict__ labels,
                             float* __restrict__ out) {
    __shared__ int h[128];
    __shared__ float wsum[16];
    int tid = threadIdx.x;
    if (tid < 128) h[tid] = 0;
    __syncthreads();
    for (int i = tid; i < B_SIZE; i += 1024) atomicAdd(&h[labels[i] & 127], 1);
    __syncthreads();
    float acc = 0.f;
    for (int idx = tid; idx < 2 * N_SIZE; idx += 1024) {
        int i = idx & (N_SIZE - 1);
        float M = 2.0f * (float)h[labels[i & (B_SIZE - 1)] & 127] - 1.0f;
        acc += logf(Sarr[idx]) - 10.0f * Aarr[idx] / M;
    }
#pragma unroll
    for (int off = 32; off > 0; off >>= 1) acc += __shfl_xor(acc, off);
    int wv = tid >> 6, ln = tid & 63;
    if (ln == 0) wsum[wv] = acc;
    __syncthreads();
    if (tid == 0) {
        float tot = 0.f;
#pragma unroll
        for (int k = 0; k < 16; ++k) tot += wsum[k];
        out[0] = tot / 16384.0f;
    }
}

extern "C" void kernel_launch(void* const* d_in, const int* in_sizes, int n_in,
                              void* d_out, int out_size, void* d_ws, size_t ws_size,
                              hipStream_t stream) {
    const float* hs     = (const float*)d_in[0];
    const float* ht0    = (const float*)d_in[1];
    const float* ht1    = (const float*)d_in[2];
    const int*   labels = (const int*)d_in[3];

    char* ws = (char*)d_ws;
    float* Sarr = (float*)(ws);
    float* Aarr = (float*)(ws + 65536);
    __hip_bfloat16* featS  = (__hip_bfloat16*)(ws + 131072);
    __hip_bfloat16* featT0 = (__hip_bfloat16*)(ws + 131072 + 2097152);
    __hip_bfloat16* featT1 = (__hip_bfloat16*)(ws + 131072 + 2 * 2097152);

    norm_kernel<<<3 * 4096, 256, 0, stream>>>(hs, ht0, ht1, featS, Sarr);
    sim_kernel<<<dim3(64, 2, NCHUNK), 256, 0, stream>>>(featS, featT0, featT1, labels, Sarr, Aarr);
    final_kernel<<<1, 1024, 0, stream>>>(Sarr, Aarr, labels, (float*)d_out);
}